// Round 8
// baseline (444.194 us; speedup 1.0000x reference)
//
#include <hip/hip_runtime.h>
#include <hip/hip_bf16.h>
#include <cstdint>

typedef __attribute__((ext_vector_type(4))) float f32x4;
typedef __attribute__((ext_vector_type(16))) float f32x16;
typedef __attribute__((ext_vector_type(8))) __bf16 bf16x8;
typedef __attribute__((ext_vector_type(4))) __bf16 bf16x4;
typedef __attribute__((ext_vector_type(4))) uint32_t u32x4;
typedef __attribute__((ext_vector_type(2))) unsigned int u32x2;

#define EPI_BF16  0
#define EPI_GELU  1
#define EPI_RES   2
#define EPI_PART  3
#define EPI_PARTB 4

__device__ __forceinline__ void gll16(const void* g, void* l) {
  __builtin_amdgcn_global_load_lds((__attribute__((address_space(1))) void*)(g),
                                   (__attribute__((address_space(3))) void*)(l), 16, 0, 0);
}

// ---------------- weight convert+transpose, all 4 weights in one launch ----------------
__global__ __launch_bounds__(256)
void convT_all(const float* __restrict__ W0, __bf16* __restrict__ T0,
               const float* __restrict__ W1, __bf16* __restrict__ T1,
               const float* __restrict__ W2, __bf16* __restrict__ T2,
               const float* __restrict__ W3, __bf16* __restrict__ T3)
{
  __shared__ __bf16 t[64][72];
  const int bid = blockIdx.x;
  const float* W; __bf16* WT; int Kd, Nd, nx, lb;
  if (bid < 768)       { W = W0; WT = T0; Kd = 1024; Nd = 3072; nx = 48; lb = bid; }
  else if (bid < 1024) { W = W1; WT = T1; Kd = 1024; Nd = 1024; nx = 16; lb = bid - 768; }
  else if (bid < 2048) { W = W2; WT = T2; Kd = 1024; Nd = 4096; nx = 64; lb = bid - 1024; }
  else                 { W = W3; WT = T3; Kd = 4096; Nd = 1024; nx = 16; lb = bid - 2048; }
  const int tid = threadIdx.x;
  const int n0 = (lb % nx) * 64, k0 = (lb / nx) * 64;
#pragma unroll
  for (int i = 0; i < 4; ++i) {
    const int c = i * 256 + tid;
    const int r = c >> 4, cc = (c & 15) * 4;
    const float4 v = *(const float4*)(W + (size_t)(k0 + r) * Nd + n0 + cc);
    bf16x4 tv; tv[0] = (__bf16)v.x; tv[1] = (__bf16)v.y; tv[2] = (__bf16)v.z; tv[3] = (__bf16)v.w;
    *(bf16x4*)&t[r][cc] = tv;
  }
  __syncthreads();
#pragma unroll
  for (int i = 0; i < 2; ++i) {
    const int c = i * 256 + tid;
    const int n = c >> 3, s = (c & 7) * 8;
    bf16x8 o;
#pragma unroll
    for (int j = 0; j < 8; ++j) o[j] = t[s + j][n];
    *(bf16x8*)(WT + (size_t)(n0 + n) * Kd + k0 + s) = o;
  }
}

// ---------------- LayerNorm rows of 1024, fp32 in -> bf16 out ----------------
__global__ __launch_bounds__(256)
void ln_rows(const float* __restrict__ x, const float* __restrict__ g,
             const float* __restrict__ b, __bf16* __restrict__ out)
{
  const int row = blockIdx.x;
  const int tid = threadIdx.x;
  const float4 v = *(const float4*)(x + (size_t)row * 1024 + tid * 4);
  float s = v.x + v.y + v.z + v.w;
  float q = v.x * v.x + v.y * v.y + v.z * v.z + v.w * v.w;
#pragma unroll
  for (int o = 32; o; o >>= 1) { s += __shfl_xor(s, o); q += __shfl_xor(q, o); }
  __shared__ float red[8];
  const int wid = tid >> 6;
  if ((tid & 63) == 0) { red[wid] = s; red[4 + wid] = q; }
  __syncthreads();
  s = red[0] + red[1] + red[2] + red[3];
  q = red[4] + red[5] + red[6] + red[7];
  const float mu = s * (1.0f / 1024.0f);
  const float var = q * (1.0f / 1024.0f) - mu * mu;
  const float rs = rsqrtf(var + 1e-5f);
  bf16x4 o4;
#pragma unroll
  for (int i = 0; i < 4; ++i) {
    const int c = tid * 4 + i;
    const float xv = (&v.x)[i];
    o4[i] = (__bf16)((xv - mu) * rs * g[c] + b[c]);
  }
  *(bf16x4*)(out + (size_t)row * 1024 + tid * 4) = o4;
}

// ---------------- fused: x2 = P0+P1+bias+R ; h2 = LN(x2)*g+b ----------------
__global__ __launch_bounds__(256)
void reduce2_ln(const float* __restrict__ P, const float* __restrict__ bias,
                const float* __restrict__ R, const float* __restrict__ g,
                const float* __restrict__ b, float* __restrict__ x2,
                __bf16* __restrict__ h2, int MN)
{
  const int row = blockIdx.x;
  const int tid = threadIdx.x;
  const size_t e = (size_t)row * 1024 + tid * 4;
  const float4 a  = *(const float4*)(P + e);
  const float4 p2 = *(const float4*)(P + (size_t)MN + e);
  const float4 r  = *(const float4*)(R + e);
  const float4 bi = *(const float4*)(bias + tid * 4);
  float v[4];
  v[0] = a.x + p2.x + r.x + bi.x;
  v[1] = a.y + p2.y + r.y + bi.y;
  v[2] = a.z + p2.z + r.z + bi.z;
  v[3] = a.w + p2.w + r.w + bi.w;
  *(float4*)(x2 + e) = *(float4*)v;
  float s = v[0] + v[1] + v[2] + v[3];
  float q = v[0]*v[0] + v[1]*v[1] + v[2]*v[2] + v[3]*v[3];
#pragma unroll
  for (int o = 32; o; o >>= 1) { s += __shfl_xor(s, o); q += __shfl_xor(q, o); }
  __shared__ float red[8];
  const int wid = tid >> 6;
  if ((tid & 63) == 0) { red[wid] = s; red[4 + wid] = q; }
  __syncthreads();
  s = red[0] + red[1] + red[2] + red[3];
  q = red[4] + red[5] + red[6] + red[7];
  const float mu = s * (1.0f / 1024.0f);
  const float var = q * (1.0f / 1024.0f) - mu * mu;
  const float rs = rsqrtf(var + 1e-5f);
  bf16x4 o4;
#pragma unroll
  for (int i = 0; i < 4; ++i) {
    const int c = tid * 4 + i;
    o4[i] = (__bf16)((v[i] - mu) * rs * g[c] + b[c]);
  }
  *(bf16x4*)(h2 + e) = o4;
}

// ---------------- GEMM: C[M,N] = A[M,K](bf16) * W, W given as WT[N,K](bf16) ----------------
template<int EPI>
__global__ __launch_bounds__(256)
void gemm_bt(const __bf16* __restrict__ A, const __bf16* __restrict__ BT,
             const float* __restrict__ bias, const float* __restrict__ R,
             void* __restrict__ Out, int M, int N, int K)
{
  const int tid = threadIdx.x;
  const int lane = tid & 63, wid = tid >> 6;
  const int l15 = lane & 15, lg = lane >> 4;
  const int wm = (wid >> 1) * 64, wn = (wid & 1) * 64;
  const int nwg = gridDim.x * gridDim.y;
  const int hw = blockIdx.y * gridDim.x + blockIdx.x;
  const int logical = (hw & 7) * (nwg >> 3) + (hw >> 3);
  const int rowBase = (logical / gridDim.x) * 128;
  const int colBase = (logical % gridDim.x) * 128;
  const int kLen = K / gridDim.z;
  const int kBeg = blockIdx.z * kLen;
  __shared__ __bf16 As[2][128 * 32];
  __shared__ __bf16 Bs[2][128 * 32];
  f32x4 acc[4][4] = {};
  const int fsw = ((l15 >> 1) & 3) << 3;

  auto STAGE = [&](int buf, int k0) {
#pragma unroll
    for (int i = 0; i < 2; ++i) {
      const int c = i * 256 + tid;
      const int r = c >> 2;
      const int s = ((c & 3) ^ ((r >> 1) & 3)) * 8;
      gll16(A + (size_t)(rowBase + r) * K + (k0 + s), &As[buf][c * 8]);
      gll16(BT + (size_t)(colBase + r) * K + (k0 + s), &Bs[buf][c * 8]);
    }
  };

  STAGE(0, kBeg);
  __syncthreads();
  int cur = 0;
  const int kEnd = kBeg + kLen;
  for (int k0 = kBeg; k0 < kEnd; k0 += 32) {
    if (k0 + 32 < kEnd) STAGE(cur ^ 1, k0 + 32);
    bf16x8 af[4], bfr[4];
#pragma unroll
    for (int m = 0; m < 4; ++m) af[m] = *(const bf16x8*)(&As[cur][(wm + m * 16 + l15) * 32 + (lg * 8 ^ fsw)]);
#pragma unroll
    for (int n = 0; n < 4; ++n) bfr[n] = *(const bf16x8*)(&Bs[cur][(wn + n * 16 + l15) * 32 + (lg * 8 ^ fsw)]);
#pragma unroll
    for (int m = 0; m < 4; ++m)
#pragma unroll
      for (int n = 0; n < 4; ++n)
        acc[m][n] = __builtin_amdgcn_mfma_f32_16x16x32_bf16(af[m], bfr[n], acc[m][n], 0, 0, 0);
    __syncthreads();
    cur ^= 1;
  }
#pragma unroll
  for (int m = 0; m < 4; ++m) {
#pragma unroll
    for (int n = 0; n < 4; ++n) {
      const int col = colBase + wn + n * 16 + l15;
      float bb = 0.0f;
      if constexpr (EPI != EPI_PART && EPI != EPI_PARTB) bb = bias[col];
#pragma unroll
      for (int i = 0; i < 4; ++i) {
        const int row = rowBase + wm + m * 16 + lg * 4 + i;
        float v = acc[m][n][i] + bb;
        if constexpr (EPI == EPI_GELU) {
          v = 0.5f * v * (1.0f + erff(v * 0.70710678118654752f));
          ((__bf16*)Out)[(size_t)row * N + col] = (__bf16)v;
        } else if constexpr (EPI == EPI_BF16) {
          ((__bf16*)Out)[(size_t)row * N + col] = (__bf16)v;
        } else if constexpr (EPI == EPI_RES) {
          v += R[(size_t)row * N + col];
          ((float*)Out)[(size_t)row * N + col] = v;
        } else if constexpr (EPI == EPI_PART) {
          ((float*)Out)[((size_t)blockIdx.z * M + row) * N + col] = v;
        } else {
          ((__bf16*)Out)[((size_t)blockIdx.z * M + row) * N + col] = (__bf16)v;
        }
      }
    }
  }
}

// ---------------- split-K reduce (4 bf16 partials): out = sum P + bias + R ----------------
__global__ __launch_bounds__(256)
void reduce4(const __bf16* __restrict__ P, const float* __restrict__ bias,
             const float* __restrict__ R, float* __restrict__ Out, int MN, int N)
{
  const size_t e = ((size_t)blockIdx.x * 256 + threadIdx.x) * 8;
  float s[8];
#pragma unroll
  for (int i = 0; i < 8; ++i) s[i] = 0.0f;
#pragma unroll
  for (int p = 0; p < 4; ++p) {
    const bf16x8 v = *(const bf16x8*)(P + (size_t)p * MN + e);
#pragma unroll
    for (int i = 0; i < 8; ++i) s[i] += (float)v[i];
  }
  const size_t col = e & (size_t)(N - 1);
  const float4 r0 = *(const float4*)(R + e),       r1 = *(const float4*)(R + e + 4);
  const float4 b0 = *(const float4*)(bias + col),  b1 = *(const float4*)(bias + col + 4);
  float4 o0, o1;
  o0.x = s[0] + r0.x + b0.x; o0.y = s[1] + r0.y + b0.y;
  o0.z = s[2] + r0.z + b0.z; o0.w = s[3] + r0.w + b0.w;
  o1.x = s[4] + r1.x + b1.x; o1.y = s[5] + r1.y + b1.y;
  o1.z = s[6] + r1.z + b1.z; o1.w = s[7] + r1.w + b1.w;
  *(float4*)(Out + e)     = o0;
  *(float4*)(Out + e + 4) = o1;
}

// ---------------- rearrange qkv[4096,3072] -> Q[bh,t,d], K[bh,t,d], VT[bh,d,t] ----------------
__global__ __launch_bounds__(256)
void rearrange(const __bf16* __restrict__ qkv, __bf16* __restrict__ Q,
               __bf16* __restrict__ Kb, __bf16* __restrict__ VT)
{
  __shared__ __bf16 vt[64][72];
  const int tid = threadIdx.x;
  const int bid = blockIdx.x;
  const int bh = bid >> 5, tt = bid & 31;
  const int b = bh >> 4, h = bh & 15;
  const int t0 = tt * 64;
#pragma unroll
  for (int i = 0; i < 2; ++i) {
    const int c = i * 256 + tid;
    const int tk = c >> 3, d0 = (c & 7) * 8;
    const size_t srow = (size_t)(b * 2048 + t0 + tk) * 3072 + h * 64 + d0;
    const size_t drow = (size_t)(bh * 2048 + t0 + tk) * 64 + d0;
    *(bf16x8*)(Q + drow) = *(const bf16x8*)(qkv + srow);
    *(bf16x8*)(Kb + drow) = *(const bf16x8*)(qkv + srow + 1024);
    *(bf16x8*)&vt[tk][d0] = *(const bf16x8*)(qkv + srow + 2048);
  }
  __syncthreads();
#pragma unroll
  for (int i = 0; i < 2; ++i) {
    const int c = i * 256 + tid;
    const int d = c >> 3, s = (c & 7) * 8;
    bf16x8 o;
#pragma unroll
    for (int j = 0; j < 8; ++j) o[j] = vt[s + j][d];
    *(bf16x8*)(VT + (size_t)(bh * 64 + d) * 2048 + t0 + s) = o;
  }
}

// ---------------- flash attention, causal; NO LDS — K/VT fragments read direct from L2 ----
// 2 independent waves per block, 32 q-rows each. Swapped QK^T (S^T=K·Q^T), in-register
// softmax (exp2 domain, defer-max THR=8), P->A-frag via cvt_pk+permlane32_swap.
__global__ __launch_bounds__(128)
void attn(const __bf16* __restrict__ Q, const __bf16* __restrict__ K,
          const __bf16* __restrict__ VT, __bf16* __restrict__ O)
{
  const int bid = blockIdx.x;
  const int bh = bid >> 5, qt = 31 - (bid & 31);   // LPT: longest q-tiles first
  const int tid = threadIdx.x;
  const int lane = tid & 63, w = tid >> 6;
  const int l31 = lane & 31, hi = lane >> 5;
  const size_t base = (size_t)bh * 2048 * 64;
  const int qrow0 = qt * 64 + w * 32;
  const float KS = 0.18033688011112042f;  // 0.125 * log2(e)

  bf16x8 qf[4];
#pragma unroll
  for (int s = 0; s < 4; ++s)
    qf[s] = *(const bf16x8*)(Q + base + (size_t)(qrow0 + l31) * 64 + s * 16 + hi * 8);

  f32x16 oa0 = {}, oa1 = {};
  float ms = -INFINITY, lst = 0.0f;

  const __bf16* Krow0 = K + base + (size_t)l31 * 64;
  const __bf16* Krow1 = K + base + (size_t)(32 + l31) * 64;
  const __bf16* Vrow0 = VT + base + (size_t)l31 * 2048;
  const __bf16* Vrow1 = VT + base + (size_t)(32 + l31) * 2048;

  for (int j = 0; j <= qt; ++j) {
    f32x16 s0v = {}, s1v = {};
#pragma unroll
    for (int s = 0; s < 4; ++s) {
      const int co = s * 16 + hi * 8;
      bf16x8 ak0 = *(const bf16x8*)(Krow0 + (size_t)j * 4096 + co);
      bf16x8 ak1 = *(const bf16x8*)(Krow1 + (size_t)j * 4096 + co);
      s0v = __builtin_amdgcn_mfma_f32_32x32x16_bf16(ak0, qf[s], s0v, 0, 0, 0);
      s1v = __builtin_amdgcn_mfma_f32_32x32x16_bf16(ak1, qf[s], s1v, 0, 0, 0);
    }
    if (j == qt) {
      const int qg = qrow0 + l31;
#pragma unroll
      for (int rg = 0; rg < 16; ++rg) {
        const int kr = j * 64 + ((rg & 3) + 8 * (rg >> 2)) + 4 * hi;
        if (kr > qg) s0v[rg] = -INFINITY;
        if (kr + 32 > qg) s1v[rg] = -INFINITY;
      }
    }
    float mx = fmaxf(s0v[0], s1v[0]);
#pragma unroll
    for (int rg = 1; rg < 16; ++rg) mx = fmaxf(mx, fmaxf(s0v[rg], s1v[rg]));
    mx = fmaxf(mx, __shfl_xor(mx, 32));
    const float mxs = mx * KS;
    if (!__all(mxs - ms <= 8.0f)) {
      const float msn = fmaxf(ms, mxs);
      const float cf = exp2f(ms - msn);
      lst *= cf;
      ms = msn;
#pragma unroll
      for (int rg = 0; rg < 16; ++rg) {
        const float cb = __shfl(cf, (rg & 3) + 8 * (rg >> 2) + 4 * hi);
        oa0[rg] *= cb; oa1[rg] *= cb;
      }
    }
    float rs = 0.0f;
#pragma unroll
    for (int rg = 0; rg < 16; ++rg) {
      const float p0 = exp2f(fmaf(s0v[rg], KS, -ms));
      const float p1 = exp2f(fmaf(s1v[rg], KS, -ms));
      s0v[rg] = p0; s1v[rg] = p1;
      rs += p0 + p1;
    }
    rs += __shfl_xor(rs, 32);
    lst += rs;
#pragma unroll
    for (int s = 0; s < 4; ++s) {
      const int br = (s & 1) * 8;
      uint32_t wA0, wA1, wB0, wB1;
      if (s < 2) {
        asm("v_cvt_pk_bf16_f32 %0, %1, %2" : "=v"(wA0) : "v"(s0v[br + 0]), "v"(s0v[br + 1]));
        asm("v_cvt_pk_bf16_f32 %0, %1, %2" : "=v"(wA1) : "v"(s0v[br + 2]), "v"(s0v[br + 3]));
        asm("v_cvt_pk_bf16_f32 %0, %1, %2" : "=v"(wB0) : "v"(s0v[br + 4]), "v"(s0v[br + 5]));
        asm("v_cvt_pk_bf16_f32 %0, %1, %2" : "=v"(wB1) : "v"(s0v[br + 6]), "v"(s0v[br + 7]));
      } else {
        asm("v_cvt_pk_bf16_f32 %0, %1, %2" : "=v"(wA0) : "v"(s1v[br + 0]), "v"(s1v[br + 1]));
        asm("v_cvt_pk_bf16_f32 %0, %1, %2" : "=v"(wA1) : "v"(s1v[br + 2]), "v"(s1v[br + 3]));
        asm("v_cvt_pk_bf16_f32 %0, %1, %2" : "=v"(wB0) : "v"(s1v[br + 4]), "v"(s1v[br + 5]));
        asm("v_cvt_pk_bf16_f32 %0, %1, %2" : "=v"(wB1) : "v"(s1v[br + 6]), "v"(s1v[br + 7]));
      }
      const u32x2 r0 = __builtin_amdgcn_permlane32_swap(wA0, wB0, false, false);
      const u32x2 r1 = __builtin_amdgcn_permlane32_swap(wA1, wB1, false, false);
      u32x4 uu; uu.x = r0.x; uu.y = r1.x; uu.z = r0.y; uu.w = r1.y;
      const bf16x8 pa = __builtin_bit_cast(bf16x8, uu);
      const int co = s * 16 + hi * 8;
      bf16x8 bv0 = *(const bf16x8*)(Vrow0 + (size_t)j * 64 + co);
      bf16x8 bv1 = *(const bf16x8*)(Vrow1 + (size_t)j * 64 + co);
      oa0 = __builtin_amdgcn_mfma_f32_32x32x16_bf16(pa, bv0, oa0, 0, 0, 0);
      oa1 = __builtin_amdgcn_mfma_f32_32x32x16_bf16(pa, bv1, oa1, 0, 0, 0);
    }
  }
  const float inv = 1.0f / lst;
  const int b = bh >> 4, hd = bh & 15;
#pragma unroll
  for (int rg = 0; rg < 16; ++rg) {
    const int cr = (rg & 3) + 8 * (rg >> 2) + 4 * hi;
    const float ib = __shfl(inv, cr);
    const int qr = qrow0 + cr;
    O[(size_t)(b * 2048 + qr) * 1024 + hd * 64 + l31]      = (__bf16)(oa0[rg] * ib);
    O[(size_t)(b * 2048 + qr) * 1024 + hd * 64 + 32 + l31] = (__bf16)(oa1[rg] * ib);
  }
}

// ---------------- host ----------------
extern "C" void kernel_launch(void* const* d_in, const int* in_sizes, int n_in,
                              void* d_out, int out_size, void* d_ws, size_t ws_size,
                              hipStream_t stream)
{
  const float* x      = (const float*)d_in[0];
  const float* ln1_g  = (const float*)d_in[1];
  const float* ln1_b  = (const float*)d_in[2];
  const float* qkv_w  = (const float*)d_in[3];
  const float* qkv_b  = (const float*)d_in[4];
  const float* proj_w = (const float*)d_in[5];
  const float* proj_b = (const float*)d_in[6];
  const float* ln2_g  = (const float*)d_in[7];
  const float* ln2_b  = (const float*)d_in[8];
  const float* mlp_w1 = (const float*)d_in[9];
  const float* mlp_b1 = (const float*)d_in[10];
  const float* mlp_w2 = (const float*)d_in[11];
  const float* mlp_b2 = (const float*)d_in[12];

  char* ws = (char*)d_ws;
  __bf16* qkvT  = (__bf16*)(ws + 0);
  __bf16* projT = (__bf16*)(ws + 6291456);
  __bf16* w1T   = (__bf16*)(ws + 8388608);
  __bf16* w2T   = (__bf16*)(ws + 16777216);
  float*  x2    = (float*) (ws + 25165824);
  __bf16* h1    = (__bf16*)(ws + 41943040);
  float*  partP = (float*) (ws + 41943040);
  __bf16* part2 = (__bf16*)(ws + 41943040);
  __bf16* qkv   = (__bf16*)(ws + 50331648);
  __bf16* Qb    = (__bf16*)(ws + 75497472);
  __bf16* h2    = (__bf16*)(ws + 75497472);
  __bf16* Kb    = (__bf16*)(ws + 83886080);
  __bf16* act1  = (__bf16*)(ws + 83886080);
  __bf16* VTb   = (__bf16*)(ws + 92274688);
  __bf16* attO  = (__bf16*)(ws + 100663296);

  convT_all<<<3072, 256, 0, stream>>>(qkv_w, qkvT, proj_w, projT, mlp_w1, w1T, mlp_w2, w2T);

  ln_rows<<<4096, 256, 0, stream>>>(x, ln1_g, ln1_b, h1);
  gemm_bt<EPI_BF16><<<dim3(24, 32), 256, 0, stream>>>(h1, qkvT, qkv_b, nullptr, qkv, 4096, 3072, 1024);
  rearrange<<<1024, 256, 0, stream>>>(qkv, Qb, Kb, VTb);
  attn<<<1024, 128, 0, stream>>>(Qb, Kb, VTb, attO);
  gemm_bt<EPI_PART><<<dim3(8, 32, 2), 256, 0, stream>>>(attO, projT, nullptr, nullptr, partP, 4096, 1024, 1024);
  reduce2_ln<<<4096, 256, 0, stream>>>(partP, proj_b, x, ln2_g, ln2_b, x2, h2, 4096 * 1024);
  gemm_bt<EPI_GELU><<<dim3(32, 32), 256, 0, stream>>>(h2, w1T, mlp_b1, nullptr, act1, 4096, 4096, 1024);
  gemm_bt<EPI_PARTB><<<dim3(8, 32, 4), 256, 0, stream>>>(act1, w2T, nullptr, nullptr, part2, 4096, 1024, 4096);
  reduce4<<<2048, 256, 0, stream>>>(part2, mlp_b2, x2, (float*)d_out, 4096 * 1024, 1024);
}

// Round 9
// 404.862 us; speedup vs baseline: 1.0971x; 1.0971x over previous
//
#include <hip/hip_runtime.h>
#include <hip/hip_bf16.h>
#include <cstdint>

typedef __attribute__((ext_vector_type(4))) float f32x4;
typedef __attribute__((ext_vector_type(16))) float f32x16;
typedef __attribute__((ext_vector_type(8))) __bf16 bf16x8;
typedef __attribute__((ext_vector_type(4))) __bf16 bf16x4;
typedef __attribute__((ext_vector_type(4))) uint32_t u32x4;
typedef __attribute__((ext_vector_type(2))) unsigned int u32x2;

#define EPI_BF16  0
#define EPI_GELU  1
#define EPI_RES   2
#define EPI_PART  3
#define EPI_PARTB 4

__device__ __forceinline__ void gll16(const void* g, void* l) {
  __builtin_amdgcn_global_load_lds((__attribute__((address_space(1))) void*)(g),
                                   (__attribute__((address_space(3))) void*)(l), 16, 0, 0);
}

// ---------------- weight convert+transpose, all 4 weights in one launch ----------------
__global__ __launch_bounds__(256)
void convT_all(const float* __restrict__ W0, __bf16* __restrict__ T0,
               const float* __restrict__ W1, __bf16* __restrict__ T1,
               const float* __restrict__ W2, __bf16* __restrict__ T2,
               const float* __restrict__ W3, __bf16* __restrict__ T3)
{
  __shared__ __bf16 t[64][72];
  const int bid = blockIdx.x;
  const float* W; __bf16* WT; int Kd, Nd, nx, lb;
  if (bid < 768)       { W = W0; WT = T0; Kd = 1024; Nd = 3072; nx = 48; lb = bid; }
  else if (bid < 1024) { W = W1; WT = T1; Kd = 1024; Nd = 1024; nx = 16; lb = bid - 768; }
  else if (bid < 2048) { W = W2; WT = T2; Kd = 1024; Nd = 4096; nx = 64; lb = bid - 1024; }
  else                 { W = W3; WT = T3; Kd = 4096; Nd = 1024; nx = 16; lb = bid - 2048; }
  const int tid = threadIdx.x;
  const int n0 = (lb % nx) * 64, k0 = (lb / nx) * 64;
#pragma unroll
  for (int i = 0; i < 4; ++i) {
    const int c = i * 256 + tid;
    const int r = c >> 4, cc = (c & 15) * 4;
    const float4 v = *(const float4*)(W + (size_t)(k0 + r) * Nd + n0 + cc);
    bf16x4 tv; tv[0] = (__bf16)v.x; tv[1] = (__bf16)v.y; tv[2] = (__bf16)v.z; tv[3] = (__bf16)v.w;
    *(bf16x4*)&t[r][cc] = tv;
  }
  __syncthreads();
#pragma unroll
  for (int i = 0; i < 2; ++i) {
    const int c = i * 256 + tid;
    const int n = c >> 3, s = (c & 7) * 8;
    bf16x8 o;
#pragma unroll
    for (int j = 0; j < 8; ++j) o[j] = t[s + j][n];
    *(bf16x8*)(WT + (size_t)(n0 + n) * Kd + k0 + s) = o;
  }
}

// ---------------- LayerNorm rows of 1024, fp32 in -> bf16 out ----------------
__global__ __launch_bounds__(256)
void ln_rows(const float* __restrict__ x, const float* __restrict__ g,
             const float* __restrict__ b, __bf16* __restrict__ out)
{
  const int row = blockIdx.x;
  const int tid = threadIdx.x;
  const float4 v = *(const float4*)(x + (size_t)row * 1024 + tid * 4);
  float s = v.x + v.y + v.z + v.w;
  float q = v.x * v.x + v.y * v.y + v.z * v.z + v.w * v.w;
#pragma unroll
  for (int o = 32; o; o >>= 1) { s += __shfl_xor(s, o); q += __shfl_xor(q, o); }
  __shared__ float red[8];
  const int wid = tid >> 6;
  if ((tid & 63) == 0) { red[wid] = s; red[4 + wid] = q; }
  __syncthreads();
  s = red[0] + red[1] + red[2] + red[3];
  q = red[4] + red[5] + red[6] + red[7];
  const float mu = s * (1.0f / 1024.0f);
  const float var = q * (1.0f / 1024.0f) - mu * mu;
  const float rs = rsqrtf(var + 1e-5f);
  bf16x4 o4;
#pragma unroll
  for (int i = 0; i < 4; ++i) {
    const int c = tid * 4 + i;
    const float xv = (&v.x)[i];
    o4[i] = (__bf16)((xv - mu) * rs * g[c] + b[c]);
  }
  *(bf16x4*)(out + (size_t)row * 1024 + tid * 4) = o4;
}

// ---------------- fused: x2 = P0+P1+bias+R ; h2 = LN(x2)*g+b ----------------
__global__ __launch_bounds__(256)
void reduce2_ln(const float* __restrict__ P, const float* __restrict__ bias,
                const float* __restrict__ R, const float* __restrict__ g,
                const float* __restrict__ b, float* __restrict__ x2,
                __bf16* __restrict__ h2, int MN)
{
  const int row = blockIdx.x;
  const int tid = threadIdx.x;
  const size_t e = (size_t)row * 1024 + tid * 4;
  const float4 a  = *(const float4*)(P + e);
  const float4 p2 = *(const float4*)(P + (size_t)MN + e);
  const float4 r  = *(const float4*)(R + e);
  const float4 bi = *(const float4*)(bias + tid * 4);
  float v[4];
  v[0] = a.x + p2.x + r.x + bi.x;
  v[1] = a.y + p2.y + r.y + bi.y;
  v[2] = a.z + p2.z + r.z + bi.z;
  v[3] = a.w + p2.w + r.w + bi.w;
  *(float4*)(x2 + e) = *(float4*)v;
  float s = v[0] + v[1] + v[2] + v[3];
  float q = v[0]*v[0] + v[1]*v[1] + v[2]*v[2] + v[3]*v[3];
#pragma unroll
  for (int o = 32; o; o >>= 1) { s += __shfl_xor(s, o); q += __shfl_xor(q, o); }
  __shared__ float red[8];
  const int wid = tid >> 6;
  if ((tid & 63) == 0) { red[wid] = s; red[4 + wid] = q; }
  __syncthreads();
  s = red[0] + red[1] + red[2] + red[3];
  q = red[4] + red[5] + red[6] + red[7];
  const float mu = s * (1.0f / 1024.0f);
  const float var = q * (1.0f / 1024.0f) - mu * mu;
  const float rs = rsqrtf(var + 1e-5f);
  bf16x4 o4;
#pragma unroll
  for (int i = 0; i < 4; ++i) {
    const int c = tid * 4 + i;
    o4[i] = (__bf16)((v[i] - mu) * rs * g[c] + b[c]);
  }
  *(bf16x4*)(h2 + e) = o4;
}

// ---------------- GEMM: C[M,N] = A[M,K](bf16) * W, W given as WT[N,K](bf16) ----------------
template<int EPI>
__global__ __launch_bounds__(256)
void gemm_bt(const __bf16* __restrict__ A, const __bf16* __restrict__ BT,
             const float* __restrict__ bias, const float* __restrict__ R,
             void* __restrict__ Out, int M, int N, int K)
{
  const int tid = threadIdx.x;
  const int lane = tid & 63, wid = tid >> 6;
  const int l15 = lane & 15, lg = lane >> 4;
  const int wm = (wid >> 1) * 64, wn = (wid & 1) * 64;
  const int nwg = gridDim.x * gridDim.y;
  const int hw = blockIdx.y * gridDim.x + blockIdx.x;
  const int logical = (hw & 7) * (nwg >> 3) + (hw >> 3);
  const int rowBase = (logical / gridDim.x) * 128;
  const int colBase = (logical % gridDim.x) * 128;
  const int kLen = K / gridDim.z;
  const int kBeg = blockIdx.z * kLen;
  __shared__ __bf16 As[2][128 * 32];
  __shared__ __bf16 Bs[2][128 * 32];
  f32x4 acc[4][4] = {};
  const int fsw = ((l15 >> 1) & 3) << 3;

  auto STAGE = [&](int buf, int k0) {
#pragma unroll
    for (int i = 0; i < 2; ++i) {
      const int c = i * 256 + tid;
      const int r = c >> 2;
      const int s = ((c & 3) ^ ((r >> 1) & 3)) * 8;
      gll16(A + (size_t)(rowBase + r) * K + (k0 + s), &As[buf][c * 8]);
      gll16(BT + (size_t)(colBase + r) * K + (k0 + s), &Bs[buf][c * 8]);
    }
  };

  STAGE(0, kBeg);
  __syncthreads();
  int cur = 0;
  const int kEnd = kBeg + kLen;
  for (int k0 = kBeg; k0 < kEnd; k0 += 32) {
    if (k0 + 32 < kEnd) STAGE(cur ^ 1, k0 + 32);
    bf16x8 af[4], bfr[4];
#pragma unroll
    for (int m = 0; m < 4; ++m) af[m] = *(const bf16x8*)(&As[cur][(wm + m * 16 + l15) * 32 + (lg * 8 ^ fsw)]);
#pragma unroll
    for (int n = 0; n < 4; ++n) bfr[n] = *(const bf16x8*)(&Bs[cur][(wn + n * 16 + l15) * 32 + (lg * 8 ^ fsw)]);
#pragma unroll
    for (int m = 0; m < 4; ++m)
#pragma unroll
      for (int n = 0; n < 4; ++n)
        acc[m][n] = __builtin_amdgcn_mfma_f32_16x16x32_bf16(af[m], bfr[n], acc[m][n], 0, 0, 0);
    __syncthreads();
    cur ^= 1;
  }
#pragma unroll
  for (int m = 0; m < 4; ++m) {
#pragma unroll
    for (int n = 0; n < 4; ++n) {
      const int col = colBase + wn + n * 16 + l15;
      float bb = 0.0f;
      if constexpr (EPI != EPI_PART && EPI != EPI_PARTB) bb = bias[col];
#pragma unroll
      for (int i = 0; i < 4; ++i) {
        const int row = rowBase + wm + m * 16 + lg * 4 + i;
        float v = acc[m][n][i] + bb;
        if constexpr (EPI == EPI_GELU) {
          v = 0.5f * v * (1.0f + erff(v * 0.70710678118654752f));
          ((__bf16*)Out)[(size_t)row * N + col] = (__bf16)v;
        } else if constexpr (EPI == EPI_BF16) {
          ((__bf16*)Out)[(size_t)row * N + col] = (__bf16)v;
        } else if constexpr (EPI == EPI_RES) {
          v += R[(size_t)row * N + col];
          ((float*)Out)[(size_t)row * N + col] = v;
        } else if constexpr (EPI == EPI_PART) {
          ((float*)Out)[((size_t)blockIdx.z * M + row) * N + col] = v;
        } else {
          ((__bf16*)Out)[((size_t)blockIdx.z * M + row) * N + col] = (__bf16)v;
        }
      }
    }
  }
}

// ---------------- split-K reduce (4 bf16 partials): out = sum P + bias + R ----------------
__global__ __launch_bounds__(256)
void reduce4(const __bf16* __restrict__ P, const float* __restrict__ bias,
             const float* __restrict__ R, float* __restrict__ Out, int MN, int N)
{
  const size_t e = ((size_t)blockIdx.x * 256 + threadIdx.x) * 8;
  float s[8];
#pragma unroll
  for (int i = 0; i < 8; ++i) s[i] = 0.0f;
#pragma unroll
  for (int p = 0; p < 4; ++p) {
    const bf16x8 v = *(const bf16x8*)(P + (size_t)p * MN + e);
#pragma unroll
    for (int i = 0; i < 8; ++i) s[i] += (float)v[i];
  }
  const size_t col = e & (size_t)(N - 1);
  const float4 r0 = *(const float4*)(R + e),       r1 = *(const float4*)(R + e + 4);
  const float4 b0 = *(const float4*)(bias + col),  b1 = *(const float4*)(bias + col + 4);
  float4 o0, o1;
  o0.x = s[0] + r0.x + b0.x; o0.y = s[1] + r0.y + b0.y;
  o0.z = s[2] + r0.z + b0.z; o0.w = s[3] + r0.w + b0.w;
  o1.x = s[4] + r1.x + b1.x; o1.y = s[5] + r1.y + b1.y;
  o1.z = s[6] + r1.z + b1.z; o1.w = s[7] + r1.w + b1.w;
  *(float4*)(Out + e)     = o0;
  *(float4*)(Out + e + 4) = o1;
}

// ---------------- rearrange qkv[4096,3072] -> Q[bh,t,d], K[bh,t,d], VT[bh,d,t] ----------------
__global__ __launch_bounds__(256)
void rearrange(const __bf16* __restrict__ qkv, __bf16* __restrict__ Q,
               __bf16* __restrict__ Kb, __bf16* __restrict__ VT)
{
  __shared__ __bf16 vt[64][72];
  const int tid = threadIdx.x;
  const int bid = blockIdx.x;
  const int bh = bid >> 5, tt = bid & 31;
  const int b = bh >> 4, h = bh & 15;
  const int t0 = tt * 64;
#pragma unroll
  for (int i = 0; i < 2; ++i) {
    const int c = i * 256 + tid;
    const int tk = c >> 3, d0 = (c & 7) * 8;
    const size_t srow = (size_t)(b * 2048 + t0 + tk) * 3072 + h * 64 + d0;
    const size_t drow = (size_t)(bh * 2048 + t0 + tk) * 64 + d0;
    *(bf16x8*)(Q + drow) = *(const bf16x8*)(qkv + srow);
    *(bf16x8*)(Kb + drow) = *(const bf16x8*)(qkv + srow + 1024);
    *(bf16x8*)&vt[tk][d0] = *(const bf16x8*)(qkv + srow + 2048);
  }
  __syncthreads();
#pragma unroll
  for (int i = 0; i < 2; ++i) {
    const int c = i * 256 + tid;
    const int d = c >> 3, s = (c & 7) * 8;
    bf16x8 o;
#pragma unroll
    for (int j = 0; j < 8; ++j) o[j] = vt[s + j][d];
    *(bf16x8*)(VT + (size_t)(bh * 64 + d) * 2048 + t0 + s) = o;
  }
}

// ---------------- flash attention, causal; QBLK=64 (2 waves x 32 q-rows), KVBLK=64 ----------
// Round-6 structure (best measured) + K/V LDS double-buffer 2-phase (stage j+1 before
// compute j, ONE barrier/iter) + exp2-domain softmax with defer-max (THR=8 log2).
__global__ __launch_bounds__(128)
void attn(const __bf16* __restrict__ Q, const __bf16* __restrict__ K,
          const __bf16* __restrict__ VT, __bf16* __restrict__ O)
{
  const int bid = blockIdx.x;
  const int bh = bid >> 5, qt = 31 - (bid & 31);   // LPT: longest q-tiles first
  const int tid = threadIdx.x;
  const int lane = tid & 63, w = tid >> 6;
  const int l31 = lane & 31, hi = lane >> 5;
  __shared__ __bf16 Ks[2][64 * 64];
  __shared__ __bf16 Vs[2][64 * 64];
  const size_t base = (size_t)bh * 2048 * 64;
  const int qrow0 = qt * 64 + w * 32;
  const int xsw = (l31 & 7) << 3;
  const float KS = 0.18033688011112042f;  // 0.125 * log2(e)

  bf16x8 qf[4];
#pragma unroll
  for (int s = 0; s < 4; ++s)
    qf[s] = *(const bf16x8*)(Q + base + (size_t)(qrow0 + l31) * 64 + s * 16 + hi * 8);

  f32x16 oa0 = {}, oa1 = {};
  float ms = -INFINITY, lst = 0.0f;

  auto STAGE = [&](int buf, int j) {
#pragma unroll
    for (int rnd = 0; rnd < 4; ++rnd) {
      const int c = rnd * 128 + tid;
      const int r = c >> 3;
      const int e = ((c & 7) ^ (r & 7)) * 8;
      gll16(K + base + (size_t)(j * 64 + r) * 64 + e, &Ks[buf][c * 8]);
      gll16(VT + base + (size_t)r * 2048 + j * 64 + e, &Vs[buf][c * 8]);
    }
  };

  STAGE(0, 0);
  __syncthreads();
  int cur = 0;
  for (int j = 0; j <= qt; ++j) {
    if (j < qt) STAGE(cur ^ 1, j + 1);
    // S^T = K · Q^T : col(lane&31)=q, row(crow(reg,hi))=key
    f32x16 s0v = {}, s1v = {};
#pragma unroll
    for (int s = 0; s < 4; ++s) {
      const int co = (s * 16 + hi * 8) ^ xsw;
      bf16x8 ak0 = *(const bf16x8*)(&Ks[cur][l31 * 64 + co]);
      bf16x8 ak1 = *(const bf16x8*)(&Ks[cur][(32 + l31) * 64 + co]);
      s0v = __builtin_amdgcn_mfma_f32_32x32x16_bf16(ak0, qf[s], s0v, 0, 0, 0);
      s1v = __builtin_amdgcn_mfma_f32_32x32x16_bf16(ak1, qf[s], s1v, 0, 0, 0);
    }
    if (j == qt) {
      const int qg = qrow0 + l31;
#pragma unroll
      for (int rg = 0; rg < 16; ++rg) {
        const int kr = j * 64 + ((rg & 3) + 8 * (rg >> 2)) + 4 * hi;
        if (kr > qg) s0v[rg] = -INFINITY;
        if (kr + 32 > qg) s1v[rg] = -INFINITY;
      }
    }
    float mx = fmaxf(s0v[0], s1v[0]);
#pragma unroll
    for (int rg = 1; rg < 16; ++rg) mx = fmaxf(mx, fmaxf(s0v[rg], s1v[rg]));
    mx = fmaxf(mx, __shfl_xor(mx, 32));
    const float mxs = mx * KS;
    if (!__all(mxs - ms <= 8.0f)) {
      const float msn = fmaxf(ms, mxs);
      const float cf = exp2f(ms - msn);
      lst *= cf;
      ms = msn;
#pragma unroll
      for (int rg = 0; rg < 16; ++rg) {
        const float cb = __shfl(cf, (rg & 3) + 8 * (rg >> 2) + 4 * hi);
        oa0[rg] *= cb; oa1[rg] *= cb;
      }
    }
    float rs = 0.0f;
#pragma unroll
    for (int rg = 0; rg < 16; ++rg) {
      const float p0 = exp2f(fmaf(s0v[rg], KS, -ms));
      const float p1 = exp2f(fmaf(s1v[rg], KS, -ms));
      s0v[rg] = p0; s1v[rg] = p1;
      rs += p0 + p1;
    }
    rs += __shfl_xor(rs, 32);
    lst += rs;
    // P -> bf16 A-frags (cvt_pk + permlane32_swap), then O += P·V
#pragma unroll
    for (int s = 0; s < 4; ++s) {
      const int br = (s & 1) * 8;
      uint32_t wA0, wA1, wB0, wB1;
      if (s < 2) {
        asm("v_cvt_pk_bf16_f32 %0, %1, %2" : "=v"(wA0) : "v"(s0v[br + 0]), "v"(s0v[br + 1]));
        asm("v_cvt_pk_bf16_f32 %0, %1, %2" : "=v"(wA1) : "v"(s0v[br + 2]), "v"(s0v[br + 3]));
        asm("v_cvt_pk_bf16_f32 %0, %1, %2" : "=v"(wB0) : "v"(s0v[br + 4]), "v"(s0v[br + 5]));
        asm("v_cvt_pk_bf16_f32 %0, %1, %2" : "=v"(wB1) : "v"(s0v[br + 6]), "v"(s0v[br + 7]));
      } else {
        asm("v_cvt_pk_bf16_f32 %0, %1, %2" : "=v"(wA0) : "v"(s1v[br + 0]), "v"(s1v[br + 1]));
        asm("v_cvt_pk_bf16_f32 %0, %1, %2" : "=v"(wA1) : "v"(s1v[br + 2]), "v"(s1v[br + 3]));
        asm("v_cvt_pk_bf16_f32 %0, %1, %2" : "=v"(wB0) : "v"(s1v[br + 4]), "v"(s1v[br + 5]));
        asm("v_cvt_pk_bf16_f32 %0, %1, %2" : "=v"(wB1) : "v"(s1v[br + 6]), "v"(s1v[br + 7]));
      }
      const u32x2 r0 = __builtin_amdgcn_permlane32_swap(wA0, wB0, false, false);
      const u32x2 r1 = __builtin_amdgcn_permlane32_swap(wA1, wB1, false, false);
      u32x4 uu; uu.x = r0.x; uu.y = r1.x; uu.z = r0.y; uu.w = r1.y;
      const bf16x8 pa = __builtin_bit_cast(bf16x8, uu);
      const int co = (s * 16 + hi * 8) ^ xsw;
      bf16x8 bv0 = *(const bf16x8*)(&Vs[cur][l31 * 64 + co]);
      bf16x8 bv1 = *(const bf16x8*)(&Vs[cur][(32 + l31) * 64 + co]);
      oa0 = __builtin_amdgcn_mfma_f32_32x32x16_bf16(pa, bv0, oa0, 0, 0, 0);
      oa1 = __builtin_amdgcn_mfma_f32_32x32x16_bf16(pa, bv1, oa1, 0, 0, 0);
    }
    __syncthreads();
    cur ^= 1;
  }
  const float inv = 1.0f / lst;
  const int b = bh >> 4, hd = bh & 15;
#pragma unroll
  for (int rg = 0; rg < 16; ++rg) {
    const int cr = (rg & 3) + 8 * (rg >> 2) + 4 * hi;
    const float ib = __shfl(inv, cr);
    const int qr = qrow0 + cr;
    O[(size_t)(b * 2048 + qr) * 1024 + hd * 64 + l31]      = (__bf16)(oa0[rg] * ib);
    O[(size_t)(b * 2048 + qr) * 1024 + hd * 64 + 32 + l31] = (__bf16)(oa1[rg] * ib);
  }
}

// ---------------- host ----------------
extern "C" void kernel_launch(void* const* d_in, const int* in_sizes, int n_in,
                              void* d_out, int out_size, void* d_ws, size_t ws_size,
                              hipStream_t stream)
{
  const float* x      = (const float*)d_in[0];
  const float* ln1_g  = (const float*)d_in[1];
  const float* ln1_b  = (const float*)d_in[2];
  const float* qkv_w  = (const float*)d_in[3];
  const float* qkv_b  = (const float*)d_in[4];
  const float* proj_w = (const float*)d_in[5];
  const float* proj_b = (const float*)d_in[6];
  const float* ln2_g  = (const float*)d_in[7];
  const float* ln2_b  = (const float*)d_in[8];
  const float* mlp_w1 = (const float*)d_in[9];
  const float* mlp_b1 = (const float*)d_in[10];
  const float* mlp_w2 = (const float*)d_in[11];
  const float* mlp_b2 = (const float*)d_in[12];

  char* ws = (char*)d_ws;
  __bf16* qkvT  = (__bf16*)(ws + 0);
  __bf16* projT = (__bf16*)(ws + 6291456);
  __bf16* w1T   = (__bf16*)(ws + 8388608);
  __bf16* w2T   = (__bf16*)(ws + 16777216);
  float*  x2    = (float*) (ws + 25165824);
  __bf16* h1    = (__bf16*)(ws + 41943040);
  float*  partP = (float*) (ws + 41943040);
  __bf16* part2 = (__bf16*)(ws + 41943040);
  __bf16* qkv   = (__bf16*)(ws + 50331648);
  __bf16* Qb    = (__bf16*)(ws + 75497472);
  __bf16* h2    = (__bf16*)(ws + 75497472);
  __bf16* Kb    = (__bf16*)(ws + 83886080);
  __bf16* act1  = (__bf16*)(ws + 83886080);
  __bf16* VTb   = (__bf16*)(ws + 92274688);
  __bf16* attO  = (__bf16*)(ws + 100663296);

  convT_all<<<3072, 256, 0, stream>>>(qkv_w, qkvT, proj_w, projT, mlp_w1, w1T, mlp_w2, w2T);

  ln_rows<<<4096, 256, 0, stream>>>(x, ln1_g, ln1_b, h1);
  gemm_bt<EPI_BF16><<<dim3(24, 32), 256, 0, stream>>>(h1, qkvT, qkv_b, nullptr, qkv, 4096, 3072, 1024);
  rearrange<<<1024, 256, 0, stream>>>(qkv, Qb, Kb, VTb);
  attn<<<1024, 128, 0, stream>>>(Qb, Kb, VTb, attO);
  gemm_bt<EPI_PART><<<dim3(8, 32, 2), 256, 0, stream>>>(attO, projT, nullptr, nullptr, partP, 4096, 1024, 1024);
  reduce2_ln<<<4096, 256, 0, stream>>>(partP, proj_b, x, ln2_g, ln2_b, x2, h2, 4096 * 1024);
  gemm_bt<EPI_GELU><<<dim3(32, 32), 256, 0, stream>>>(h2, w1T, mlp_b1, nullptr, act1, 4096, 4096, 1024);
  gemm_bt<EPI_PARTB><<<dim3(8, 32, 4), 256, 0, stream>>>(act1, w2T, nullptr, nullptr, part2, 4096, 1024, 4096);
  reduce4<<<2048, 256, 0, stream>>>(part2, mlp_b2, x2, (float*)d_out, 4096 * 1024, 1024);
}